// Round 15
// baseline (86.851 us; speedup 1.0000x reference)
//
#include <hip/hip_runtime.h>
#include <math.h>

#define EPSF 1e-8f

typedef float f2v __attribute__((ext_vector_type(2)));

__device__ __forceinline__ float bcf(int x){ return __builtin_bit_cast(float, x); }
__device__ __forceinline__ int   bci(float x){ return __builtin_bit_cast(int, x); }

template<int CTRL, int RM>
__device__ __forceinline__ float dpp0(float v){
  return bcf(__builtin_amdgcn_update_dpp(0, bci(v), CTRL, RM, 0xF, false));
}
__device__ __forceinline__ float rl(float v, int l){
  return bcf(__builtin_amdgcn_readlane(bci(v), l));
}
__device__ __forceinline__ float wave_iscan_add(float v){
  v += dpp0<0x111,0xF>(v);
  v += dpp0<0x112,0xF>(v);
  v += dpp0<0x114,0xF>(v);
  v += dpp0<0x118,0xF>(v);
  v += dpp0<0x142,0xA>(v);
  v += dpp0<0x143,0xC>(v);
  return v;
}
__device__ __forceinline__ float wave_red_add(float v){ return wave_iscan_add(v); } // lane63 = total
__device__ __forceinline__ float wave_red_max_pos(float v){ // v >= 0
  v = fmaxf(v, dpp0<0x111,0xF>(v));
  v = fmaxf(v, dpp0<0x112,0xF>(v));
  v = fmaxf(v, dpp0<0x114,0xF>(v));
  v = fmaxf(v, dpp0<0x118,0xF>(v));
  v = fmaxf(v, dpp0<0x142,0xA>(v));
  v = fmaxf(v, dpp0<0x143,0xC>(v));
  return v;
}

// 16B-unit swizzle: slot(low3) ^= i[5:3]. Verified at the b128 floor for all
// patterns incl. stride-8 stash/read (R13: worked at 4.8e6 conflicts / 2 rows).
__device__ __forceinline__ int FL8(int i){ return i ^ ((i >> 3) & 7); }

// In-place 8-point complex DFT, packed over 2 rows (f2v = {rowA, rowB}).
__device__ __forceinline__ void dft8p(f2v* ar, f2v* ai){
  const float C = 0.70710678118654752f;
  const f2v t0r=ar[0]+ar[4], t0i=ai[0]+ai[4];
  const f2v t1r=ar[0]-ar[4], t1i=ai[0]-ai[4];
  const f2v t2r=ar[2]+ar[6], t2i=ai[2]+ai[6];
  const f2v t3r=ar[2]-ar[6], t3i=ai[2]-ai[6];
  const f2v E0r=t0r+t2r, E0i=t0i+t2i;
  const f2v E1r=t1r+t3i, E1i=t1i-t3r;
  const f2v E2r=t0r-t2r, E2i=t0i-t2i;
  const f2v E3r=t1r-t3i, E3i=t1i+t3r;
  const f2v u0r=ar[1]+ar[5], u0i=ai[1]+ai[5];
  const f2v u1r=ar[1]-ar[5], u1i=ai[1]-ai[5];
  const f2v u2r=ar[3]+ar[7], u2i=ai[3]+ai[7];
  const f2v u3r=ar[3]-ar[7], u3i=ai[3]-ai[7];
  const f2v O0r=u0r+u2r, O0i=u0i+u2i;
  const f2v O1r=u1r+u3i, O1i=u1i-u3r;
  const f2v O2r=u0r-u2r, O2i=u0i-u2i;
  const f2v O3r=u1r-u3i, O3i=u1i+u3r;
  const f2v w1r =  C*(O1r+O1i), w1i = C*(O1i-O1r);
  const f2v w2r =  O2i,         w2i = -O2r;
  const f2v w3r =  C*(O3i-O3r), w3i = -C*(O3r+O3i);
  ar[0]=E0r+O0r; ai[0]=E0i+O0i;
  ar[4]=E0r-O0r; ai[4]=E0i-O0i;
  ar[1]=E1r+w1r; ai[1]=E1i+w1i;
  ar[5]=E1r-w1r; ai[5]=E1i-w1i;
  ar[2]=E2r+w2r; ai[2]=E2i+w2i;
  ar[6]=E2r-w2r; ai[6]=E2i-w2i;
  ar[3]=E3r+w3r; ai[3]=E3i+w3i;
  ar[7]=E3r-w3r; ai[7]=E3i-w3i;
}

// stats LDS slots (per wave, per row): 0 SUMSQ, 1 ALT, 2..11 R1..R10, 12 STR,
// 13 STR2, 14 SC, 15 SC2, 16 SUMX, 17..26 Slo, 27..36 Shi pool, 37 x0, 38 xl
__global__ void __launch_bounds__(128, 2)
sr_kernel(const float* __restrict__ x,
          const float* __restrict__ ln_w, const float* __restrict__ ln_b,
          const float* __restrict__ w1, const float* __restrict__ b1,
          const float* __restrict__ w2, const float* __restrict__ b2,
          float* __restrict__ out, int B)
{
  // packed complex buffer: unit u holds [Are, Bre, Aim, Bim] (16B)
  __shared__ __align__(16) float bufr2[2][2048];    // 8KB per wave
  __shared__ __align__(16) float stats2[2][2][40];

  const int tid = threadIdx.x;
  const int t   = tid & 63;
  const int wv  = tid >> 6;
  const int rowbase = blockIdx.x * 4 + wv * 2;
  if (rowbase >= B) return;
  float* buff = bufr2[wv];
  float* stA  = stats2[wv][0];
  float* stB  = stats2[wv][1];

  // ======== phase 1 (per row): own-16 load, packed stash, prefix scan ========
  float exclA, exclB;
  auto phase1 = [&](int rr, float& excl_out) {
    const float* __restrict__ xr = x + (size_t)(rowbase + rr) * 1024;
    float* st = rr ? stB : stA;
    const int c0 = t * 16;
    float vv[16];
    {
      const float4 a0 = *reinterpret_cast<const float4*>(xr + c0);
      const float4 a1 = *reinterpret_cast<const float4*>(xr + c0 + 4);
      const float4 a2 = *reinterpret_cast<const float4*>(xr + c0 + 8);
      const float4 a3 = *reinterpret_cast<const float4*>(xr + c0 + 12);
      vv[0]=a0.x; vv[1]=a0.y; vv[2]=a0.z; vv[3]=a0.w;
      vv[4]=a1.x; vv[5]=a1.y; vv[6]=a1.z; vv[7]=a1.w;
      vv[8]=a2.x; vv[9]=a2.y; vv[10]=a2.z; vv[11]=a2.w;
      vv[12]=a3.x; vv[13]=a3.y; vv[14]=a3.z; vv[15]=a3.w;
    }
    // stash z[8t+j]: re at +rr, im at +2+rr
#pragma unroll
    for (int j = 0; j < 8; ++j) {
      const int fo = FL8(8*t + j) * 4 + rr;
      buff[fo]     = vv[2*j];
      buff[fo + 2] = vv[2*j + 1];
    }
    // prefix
    float s[16];
    s[0] = vv[0];
#pragma unroll
    for (int j = 1; j < 16; ++j) s[j] = s[j-1] + vv[j];
    const float cs16 = s[15];
    const float incl = wave_iscan_add(cs16);
    const float excl = incl - cs16;
    excl_out = excl;
#pragma unroll
    for (int j = 0; j < 16; ++j) s[j] += excl;
    if (t == 63) st[16] = incl;                       // SUMX
    if (t == 0) {
#pragma unroll
      for (int q = 0; q < 10; ++q) st[17 + q] = s[q];
      st[37] = vv[0];
    }
    if (t == 63) {
#pragma unroll
      for (int q = 0; q < 10; ++q) st[27 + q] = s[5 + q];
      st[38] = vv[15];
    }
  };
  phase1(0, exclA);
  phase1(1, exclB);

  // ======== phase 2 (packed over both rows, data re-read from LDS) ========
  f2v xv[28];
#pragma unroll
  for (int u = 0; u < 8; ++u) {
    const float4 q4 = *reinterpret_cast<const float4*>(&buff[FL8(8*t + u) * 4]);
    xv[2*u]   = f2v{q4.x, q4.y};
    xv[2*u+1] = f2v{q4.z, q4.w};
  }
  if (t < 63) {
#pragma unroll
    for (int u = 0; u < 6; ++u) {
      const float4 q4 = *reinterpret_cast<const float4*>(&buff[FL8(8*t + 8 + u) * 4]);
      xv[16+2*u]   = f2v{q4.x, q4.y};
      xv[16+2*u+1] = f2v{q4.z, q4.w};
    }
  } else {
#pragma unroll
    for (int j = 16; j < 28; ++j) xv[j] = f2v{0.f, 0.f};
  }
  f2v pxv[12];
  if (t > 0) {
#pragma unroll
    for (int u = 0; u < 6; ++u) {
      const float4 q4 = *reinterpret_cast<const float4*>(&buff[FL8(8*t - 6 + u) * 4]);
      pxv[2*u]   = f2v{q4.x, q4.y};
      pxv[2*u+1] = f2v{q4.z, q4.w};
    }
  } else {
#pragma unroll
    for (int j = 0; j < 12; ++j) pxv[j] = f2v{0.f, 0.f};
  }

  // packed sumsq / alt / lag products
  {
    f2v sumsq2 = {0.f,0.f}, alt2 = {0.f,0.f};
#pragma unroll
    for (int j = 0; j < 16; ++j) {
      sumsq2 += xv[j] * xv[j];
      alt2 += (j & 1) ? -xv[j] : xv[j];
    }
    float r;
    r = wave_red_add(sumsq2.x); if (t == 63) stA[0] = r;
    r = wave_red_add(sumsq2.y); if (t == 63) stB[0] = r;
    r = wave_red_add(alt2.x);   if (t == 63) stA[1] = r;
    r = wave_red_add(alt2.y);   if (t == 63) stB[1] = r;
  }
#pragma unroll
  for (int k = 1; k <= 10; ++k) {
    f2v acc = {0.f,0.f};
#pragma unroll
    for (int j = 0; j < 16; ++j) acc += xv[j] * xv[j+k];
    float r;
    r = wave_red_add(acc.x); if (t == 63) stA[1 + k] = r;
    r = wave_red_add(acc.y); if (t == 63) stB[1 + k] = r;
  }

  // packed trend (sliding +-12 window)
  const f2v x0p = f2v{stA[37], stB[37]};
  const f2v xlp = f2v{stA[38], stB[38]};
  f2v trv2[16];
  f2v strv = {0.f,0.f}, strsq = {0.f,0.f};
  {
    f2v wsum = {0.f,0.f};
#pragma unroll
    for (int j = 0; j < 12; ++j) wsum += pxv[j];
#pragma unroll
    for (int j = 0; j <= 12; ++j) wsum += xv[j];
#pragma unroll
    for (int jj = 0; jj < 16; ++jj) {
      if (jj > 0) {
        const f2v addv = xv[jj + 12];
        const f2v subv = (jj < 13) ? pxv[jj - 1] : xv[jj - 13];
        wsum += addv - subv;
      }
      f2v swc = wsum;
      if (t == 0  && jj < 12) swc += (float)(12 - jj) * x0p;
      if (t == 63 && jj >= 4) swc += (float)(jj - 3) * xlp;
      const f2v tv = swc * 0.04f;
      trv2[jj] = tv;
      strv += tv;
      strsq += tv * tv;
    }
  }
  const float tinclA = wave_iscan_add(strv.x);
  const float tinclB = wave_iscan_add(strv.y);
  if (t == 63) { stA[12] = tinclA; stB[12] = tinclB; }
  {
    float r;
    r = wave_red_add(strsq.x); if (t == 63) stA[13] = r;
    r = wave_red_add(strsq.y); if (t == 63) stB[13] = r;
  }
  // packed cumsum(resid): s[jj] recomputed on the fly = excl + prefix(xv)
  {
    f2v run  = f2v{tinclA, tinclB} - strv;   // texcl per row
    f2v pref = f2v{exclA, exclB};
    f2v sc = {0.f,0.f}, scs = {0.f,0.f};
#pragma unroll
    for (int jj = 0; jj < 16; ++jj) {
      pref += xv[jj];
      run  += trv2[jj];
      const f2v c = pref - run;
      sc  += c;
      scs += c * c;
    }
    float r;
    r = wave_red_add(sc.x);  if (t == 63) stA[14] = r;
    r = wave_red_add(sc.y);  if (t == 63) stB[14] = r;
    r = wave_red_add(scs.x); if (t == 63) stA[15] = r;
    r = wave_red_add(scs.y); if (t == 63) stB[15] = r;
  }

  // ==================== packed half-length real FFT (2 rows per wave) ====================
  f2v zr[8], zi[8];
#pragma unroll
  for (int p = 0; p < 8; ++p) {
    const float4 q4 = *reinterpret_cast<const float4*>(&buff[FL8(t + 64*p) * 4]);
    zr[p] = f2v{q4.x, q4.y};
    zi[p] = f2v{q4.z, q4.w};
  }
  dft8p(zr, zi);
  {
    const float a1 = -0.012271846303085130f * (float)t;   // -2pi/512 * t
    const float c1 = __cosf(a1), s1 = __sinf(a1);
    const float c2=c1*c1-s1*s1, s2=2.f*c1*s1;
    const float c3=c2*c1-s2*s1, s3=s2*c1+c2*s1;
    const float c4=c2*c2-s2*s2, s4=2.f*c2*s2;
    const float c5=c4*c1-s4*s1, s5=s4*c1+c4*s1;
    const float c6=c3*c3-s3*s3, s6=2.f*c3*s3;
    const float c7=c6*c1-s6*s1, s7=s6*c1+c6*s1;
    const float cq[8] = {1.f,c1,c2,c3,c4,c5,c6,c7};
    const float sq[8] = {0.f,s1,s2,s3,s4,s5,s6,s7};
#pragma unroll
    for (int q = 1; q < 8; ++q) {
      const f2v r0 = zr[q]*cq[q] - zi[q]*sq[q];
      zi[q] = zr[q]*sq[q] + zi[q]*cq[q];
      zr[q] = r0;
    }
  }
  // transpose 1: unit q*64 + t
#pragma unroll
  for (int q = 0; q < 8; ++q) {
    const int fo = FL8(q*64 + t) * 4;
    *reinterpret_cast<f2v*>(&buff[fo])     = zr[q];
    *reinterpret_cast<f2v*>(&buff[fo + 2]) = zi[q];
  }
  const int qq = t >> 3;
  const int dd = t & 7;
  const int qb = qq << 6;
#pragma unroll
  for (int e = 0; e < 8; ++e) {
    const float4 q4 = *reinterpret_cast<const float4*>(&buff[FL8(qb + dd + 8*e) * 4]);
    zr[e] = f2v{q4.x, q4.y};
    zi[e] = f2v{q4.z, q4.w};
  }
  dft8p(zr, zi);
  {
    const float a1 = -0.098174770424681039f * (float)dd;  // -2pi/64 * d
    const float c1 = __cosf(a1), s1 = __sinf(a1);
    const float c2=c1*c1-s1*s1, s2=2.f*c1*s1;
    const float c3=c2*c1-s2*s1, s3=s2*c1+c2*s1;
    const float c4=c2*c2-s2*s2, s4=2.f*c2*s2;
    const float c5=c4*c1-s4*s1, s5=s4*c1+c4*s1;
    const float c6=c3*c3-s3*s3, s6=2.f*c3*s3;
    const float c7=c6*c1-s6*s1, s7=s6*c1+c6*s1;
    const float cq[8] = {1.f,c1,c2,c3,c4,c5,c6,c7};
    const float sq[8] = {0.f,s1,s2,s3,s4,s5,s6,s7};
#pragma unroll
    for (int q = 1; q < 8; ++q) {
      const f2v r0 = zr[q]*cq[q] - zi[q]*sq[q];
      zi[q] = zr[q]*sq[q] + zi[q]*cq[q];
      zr[q] = r0;
    }
  }
  // transpose 2: unit qb + sA*8 + dd
#pragma unroll
  for (int sA = 0; sA < 8; ++sA) {
    const int fo = FL8(qb + sA*8 + dd) * 4;
    *reinterpret_cast<f2v*>(&buff[fo])     = zr[sA];
    *reinterpret_cast<f2v*>(&buff[fo + 2]) = zi[sA];
  }
#pragma unroll
  for (int d = 0; d < 8; ++d) {
    const float4 q4 = *reinterpret_cast<const float4*>(&buff[FL8(qb + dd*8 + d) * 4]);
    zr[d] = f2v{q4.x, q4.y};
    zi[d] = f2v{q4.z, q4.w};
  }
  dft8p(zr, zi);
  // register r holds Z[k] (both rows), k = 64r + 8*dd + qq

  // ---- untangle to rfft psd: write Z, read conjugate partner ----
#pragma unroll
  for (int r = 0; r < 8; ++r) {
    const int fo = FL8(t*8 + r) * 4;
    *reinterpret_cast<f2v*>(&buff[fo])     = zr[r];
    *reinterpret_cast<f2v*>(&buff[fo + 2]) = zi[r];
  }
  const int pl = (t == 0) ? 0 : ((t < 8) ? (8 - t) : (71 - t));
  const bool lane0 = (t == 0);
  const float kb = (float)((dd << 3) + qq);
  const float ab = -0.0061359231515425649f * kb;          // -pi/512 * (8s+q)
  const float wbr = __cosf(ab), wbi = __sinf(ab);
  constexpr float RCr[8] = {1.f, 0.98078528040323044f, 0.92387953251128674f, 0.83146961230254524f,
                            0.70710678118654752f, 0.55557023301960222f, 0.38268343236508977f, 0.19509032201612827f};
  constexpr float RCi[8] = {0.f, -0.19509032201612827f, -0.38268343236508977f, -0.55557023301960222f,
                            -0.70710678118654752f, -0.83146961230254524f, -0.92387953251128674f, -0.98078528040323044f};
  float psA = 0.f, psB = 0.f, pmA = 0.f, pmB = 0.f, plA = 0.f, plB = 0.f;
#pragma unroll
  for (int r = 0; r < 8; ++r) {
    const int rho = lane0 ? ((8 - r) & 7) : (7 - r);
    const float4 q4 = *reinterpret_cast<const float4*>(&buff[FL8(pl*8 + rho) * 4]);
    const f2v zpr = f2v{q4.x, q4.y};
    const f2v zpi = f2v{q4.z, q4.w};
    const f2v Er = 0.5f*(zr[r] + zpr);
    const f2v Ei = 0.5f*(zi[r] - zpi);
    const f2v Or = 0.5f*(zi[r] + zpi);
    const f2v Oi = -0.5f*(zr[r] - zpr);
    const float wr = wbr*RCr[r] - wbi*RCi[r];
    const float wi = wbr*RCi[r] + wbi*RCr[r];
    const f2v Xr = Er + wr*Or - wi*Oi;
    const f2v Xi = Ei + wr*Oi + wi*Or;
    const f2v pp = Xr*Xr + Xi*Xi;
    const float pa = fmaxf(pp.x, EPSF);
    const float pb = fmaxf(pp.y, EPSF);
    psA += pa; psB += pb;
    pmA = fmaxf(pmA, pa); pmB = fmaxf(pmB, pb);
    plA += pa * __logf(pa);
    plB += pb * __logf(pb);
  }
  float PSUM2[2], PMAX2[2], PLOG2[2];
  PSUM2[0] = rl(wave_red_add(psA), 63);
  PSUM2[1] = rl(wave_red_add(psB), 63);
  PMAX2[0] = rl(wave_red_max_pos(pmA), 63);
  PMAX2[1] = rl(wave_red_max_pos(pmB), 63);
  PLOG2[0] = rl(wave_red_add(plA), 63);
  PLOG2[1] = rl(wave_red_add(plB), 63);

  // ======== per-row tail: features, LN, MLP, stores ========
#pragma unroll 1
  for (int rr = 0; rr < 2; ++rr) {
    const float* st = stats2[wv][rr];
    const int row = rowbase + rr;
    const float PSUM = PSUM2[rr], PMAX = PMAX2[rr], PLOG = PLOG2[rr];

    const float SUMSQ = st[0];
    const float ALT   = st[1];
    const float STR   = st[12];
    const float STR2  = st[13];
    const float SC    = st[14];
    const float SC2   = st[15];
    const float SUMX  = st[16];
    const float x0    = st[37];
    const float xl    = st[38];

    const float p512b = fmaxf(ALT * ALT, EPSF);
    const float Sr    = PSUM + p512b;
    const float invS  = 1.f / Sr;
    const float PLr   = PLOG + p512b * __logf(p512b);
    const float ent   = __logf(Sr) - PLr * invS;
    const float PMX   = fmaxf(PMAX, p512b);

    const float m = SUMX * (1.f / 1024.f);
    const float den = SUMSQ - 1024.f * m * m + EPSF;
    const float invden = 1.f / den;
    float acf1 = 0.f, acf2 = 0.f, lbq = 0.f, R1v = 0.f;
#pragma unroll
    for (int k = 1; k <= 10; ++k) {
      const float Rkv = st[1 + k];
      const float Slo = st[16 + k];
      const float Shi = st[37 - k];
      const float num = Rkv - m * (Shi + (SUMX - Slo)) + (float)(1024 - k) * m * m;
      const float a = fminf(fmaxf(num * invden, -1.f), 1.f);
      if (k == 1) { acf1 = a; R1v = Rkv; }
      else if (k == 2) acf2 = a;
      lbq += a * a;
    }
    const float spent = fminf(fmaxf(ent / (__logf(513.f + EPSF) + EPSF), 0.f), 1.f);
    const float peak  = fminf(fmaxf(PMX / (Sr + EPSF), 0.f), 1.f);
    const float phi = fminf(fmaxf(R1v / ((SUMSQ - xl * xl) + EPSF), -1.f), 1.f);
    const float invn = 1.f / 1023.f;
    const float sum_d2 = 2.f * SUMSQ - x0 * x0 - xl * xl - 2.f * R1v;
    const float md = (xl - x0) * invn;
    const float diff_var = sum_d2 * invn - md * md;
    const float tstr = STR2 * (1.f / 1024.f) - (STR * (1.f / 1024.f)) * (STR * (1.f / 1024.f));
    const float varx = SUMSQ * (1.f / 1024.f) - m * m;
    const float mc = SC * (1.f / 1024.f);
    const float kpss = (SC2 * (1.f / 1024.f) - mc * mc) / (varx + 1e-8f);

    float f[9] = {acf1, acf2, spent, phi, diff_var, tstr, kpss, lbq, peak};
    float fm = 0.f;
#pragma unroll
    for (int d = 0; d < 9; ++d) fm += f[d];
    fm *= (1.f / 9.f);
    float fv = 0.f;
#pragma unroll
    for (int d = 0; d < 9; ++d) { const float tt = f[d] - fm; fv = fmaf(tt, tt, fv); }
    fv *= (1.f / 9.f);
    const float inl = 1.f / sqrtf(fv + 1e-5f);
    float fn[9];
#pragma unroll
    for (int d = 0; d < 9; ++d) fn[d] = (f[d] - fm) * inl * ln_w[d] + ln_b[d];

    float h = b1[t];
#pragma unroll
    for (int d = 0; d < 9; ++d) h = fmaf(fn[d], w1[d * 64 + t], h);
    h = fmaxf(h, 0.f);
    float l0 = h * w2[t * 3 + 0];
    float l1 = h * w2[t * 3 + 1];
    float l2 = h * w2[t * 3 + 2];
    l0 = wave_red_add(l0);
    l1 = wave_red_add(l1);
    l2 = wave_red_add(l2);
    const float L0 = rl(l0, 63) + b2[0];
    const float L1 = rl(l1, 63) + b2[1];
    const float L2 = rl(l2, 63) + b2[2];
    if (t == 0) {
      const float mx = fmaxf(L0, fmaxf(L1, L2));
      const float e0 = __expf(L0 - mx), e1 = __expf(L1 - mx), e2 = __expf(L2 - mx);
      const float is = 1.f / (e0 + e1 + e2);
      float* o = out + (size_t)row * 3;
      o[0] = e0 * is; o[1] = e1 * is; o[2] = e2 * is;
      float* fo = out + (size_t)B * 3 + (size_t)row * 9;
      fo[0] = fn[0]; fo[1] = fn[1]; fo[2] = fn[2]; fo[3] = fn[3]; fo[4] = fn[4];
      fo[5] = fn[5]; fo[6] = fn[6]; fo[7] = fn[7]; fo[8] = fn[8];
    }
  }
}

extern "C" void kernel_launch(void* const* d_in, const int* in_sizes, int n_in,
                              void* d_out, int out_size, void* d_ws, size_t ws_size,
                              hipStream_t stream) {
  (void)n_in; (void)out_size; (void)d_ws; (void)ws_size;
  const float* x    = (const float*)d_in[0];
  const float* ln_w = (const float*)d_in[1];
  const float* ln_b = (const float*)d_in[2];
  const float* w1   = (const float*)d_in[3];
  const float* b1   = (const float*)d_in[4];
  const float* w2   = (const float*)d_in[5];
  const float* b2   = (const float*)d_in[6];
  float* out = (float*)d_out;
  const int B = in_sizes[0] / 1024;
  sr_kernel<<<(B + 3) / 4, 128, 0, stream>>>(x, ln_w, ln_b, w1, b1, w2, b2, out, B);
}

// Round 16
// 82.836 us; speedup vs baseline: 1.0485x; 1.0485x over previous
//
#include <hip/hip_runtime.h>
#include <math.h>

#define EPSF 1e-8f

typedef float f2v __attribute__((ext_vector_type(2)));

__device__ __forceinline__ float bcf(int x){ return __builtin_bit_cast(float, x); }
__device__ __forceinline__ int   bci(float x){ return __builtin_bit_cast(int, x); }

template<int CTRL, int RM>
__device__ __forceinline__ float dpp0(float v){
  return bcf(__builtin_amdgcn_update_dpp(0, bci(v), CTRL, RM, 0xF, false));
}
__device__ __forceinline__ float rl(float v, int l){
  return bcf(__builtin_amdgcn_readlane(bci(v), l));
}
__device__ __forceinline__ float wave_iscan_add(float v){
  v += dpp0<0x111,0xF>(v);
  v += dpp0<0x112,0xF>(v);
  v += dpp0<0x114,0xF>(v);
  v += dpp0<0x118,0xF>(v);
  v += dpp0<0x142,0xA>(v);
  v += dpp0<0x143,0xC>(v);
  return v;
}
__device__ __forceinline__ float wave_red_add(float v){ return wave_iscan_add(v); } // lane63 = total
__device__ __forceinline__ float wave_red_max_pos(float v){ // v >= 0
  v = fmaxf(v, dpp0<0x111,0xF>(v));
  v = fmaxf(v, dpp0<0x112,0xF>(v));
  v = fmaxf(v, dpp0<0x114,0xF>(v));
  v = fmaxf(v, dpp0<0x118,0xF>(v));
  v = fmaxf(v, dpp0<0x142,0xA>(v));
  v = fmaxf(v, dpp0<0x143,0xC>(v));
  return v;
}

// 16B-unit swizzle for the packed buffer: slot(low3) ^= i[5:3]. Bijective on
// [0,512). Rank-3 lane->slot maps for all 8 patterns (stash 8t+j, readA t+64p,
// T1 w/r, T2 w/r, untangle w/r) -> 8 lanes/slot = the b128 floor.
__device__ __forceinline__ int FL8(int i){ return i ^ ((i >> 3) & 7); }

// In-place 8-point complex DFT, packed over 2 rows (f2v = {rowA, rowB}).
__device__ __forceinline__ void dft8p(f2v* ar, f2v* ai){
  const float C = 0.70710678118654752f;
  const f2v t0r=ar[0]+ar[4], t0i=ai[0]+ai[4];
  const f2v t1r=ar[0]-ar[4], t1i=ai[0]-ai[4];
  const f2v t2r=ar[2]+ar[6], t2i=ai[2]+ai[6];
  const f2v t3r=ar[2]-ar[6], t3i=ai[2]-ai[6];
  const f2v E0r=t0r+t2r, E0i=t0i+t2i;
  const f2v E1r=t1r+t3i, E1i=t1i-t3r;
  const f2v E2r=t0r-t2r, E2i=t0i-t2i;
  const f2v E3r=t1r-t3i, E3i=t1i+t3r;
  const f2v u0r=ar[1]+ar[5], u0i=ai[1]+ai[5];
  const f2v u1r=ar[1]-ar[5], u1i=ai[1]-ai[5];
  const f2v u2r=ar[3]+ar[7], u2i=ai[3]+ai[7];
  const f2v u3r=ar[3]-ar[7], u3i=ai[3]-ai[7];
  const f2v O0r=u0r+u2r, O0i=u0i+u2i;
  const f2v O1r=u1r+u3i, O1i=u1i-u3r;
  const f2v O2r=u0r-u2r, O2i=u0i-u2i;
  const f2v O3r=u1r-u3i, O3i=u1i+u3r;
  const f2v w1r =  C*(O1r+O1i), w1i = C*(O1i-O1r);
  const f2v w2r =  O2i,         w2i = -O2r;
  const f2v w3r =  C*(O3i-O3r), w3i = -C*(O3r+O3i);
  ar[0]=E0r+O0r; ai[0]=E0i+O0i;
  ar[4]=E0r-O0r; ai[4]=E0i-O0i;
  ar[1]=E1r+w1r; ai[1]=E1i+w1i;
  ar[5]=E1r-w1r; ai[5]=E1i-w1i;
  ar[2]=E2r+w2r; ai[2]=E2i+w2i;
  ar[6]=E2r-w2r; ai[6]=E2i-w2i;
  ar[3]=E3r+w3r; ai[3]=E3i+w3i;
  ar[7]=E3r-w3r; ai[7]=E3i-w3i;
}

// stats LDS slots (per wave, per row): 0 SUMSQ, 1 ALT, 2..11 R1..R10, 12 STR,
// 13 STR2, 14 SC, 15 SC2, 16 SUMX, 17..26 Slo, 27..36 Shi pool, 37 x0, 38 xl
__global__ void __launch_bounds__(128, 2)
sr_kernel(const float* __restrict__ x,
          const float* __restrict__ ln_w, const float* __restrict__ ln_b,
          const float* __restrict__ w1, const float* __restrict__ b1,
          const float* __restrict__ w2, const float* __restrict__ b2,
          float* __restrict__ out, int B)
{
  // packed complex buffer: unit u holds [Are, Bre, Aim, Bim] (16B)
  __shared__ __align__(16) float bufr2[2][2048];    // 8KB per wave
  __shared__ __align__(16) float stats2[2][2][40];

  const int tid = threadIdx.x;
  const int t   = tid & 63;
  const int wv  = tid >> 6;
  const int rowbase = blockIdx.x * 4 + wv * 2;
  if (rowbase >= B) return;
  float* buff = bufr2[wv];

  // ======== per-row scalar phase: loads, stash (packed halves), stats ========
#pragma unroll 1
  for (int rr = 0; rr < 2; ++rr) {
    const float* __restrict__ xr = x + (size_t)(rowbase + rr) * 1024;
    float* st = stats2[wv][rr];

    const int c0 = t * 16;
    float vv[28];
    {
      const float4 a0 = *reinterpret_cast<const float4*>(xr + c0);
      const float4 a1 = *reinterpret_cast<const float4*>(xr + c0 + 4);
      const float4 a2 = *reinterpret_cast<const float4*>(xr + c0 + 8);
      const float4 a3 = *reinterpret_cast<const float4*>(xr + c0 + 12);
      vv[0]=a0.x; vv[1]=a0.y; vv[2]=a0.z; vv[3]=a0.w;
      vv[4]=a1.x; vv[5]=a1.y; vv[6]=a1.z; vv[7]=a1.w;
      vv[8]=a2.x; vv[9]=a2.y; vv[10]=a2.z; vv[11]=a2.w;
      vv[12]=a3.x; vv[13]=a3.y; vv[14]=a3.z; vv[15]=a3.w;
      if (t < 63) {
        const float4 n0 = *reinterpret_cast<const float4*>(xr + c0 + 16);
        const float4 n1 = *reinterpret_cast<const float4*>(xr + c0 + 20);
        const float4 n2 = *reinterpret_cast<const float4*>(xr + c0 + 24);
        vv[16]=n0.x; vv[17]=n0.y; vv[18]=n0.z; vv[19]=n0.w;
        vv[20]=n1.x; vv[21]=n1.y; vv[22]=n1.z; vv[23]=n1.w;
        vv[24]=n2.x; vv[25]=n2.y; vv[26]=n2.z; vv[27]=n2.w;
      } else {
#pragma unroll
        for (int j = 16; j < 28; ++j) vv[j] = 0.f;
      }
    }
    float pv[12];
    if (t > 0) {
      const float4 p0 = *reinterpret_cast<const float4*>(xr + c0 - 12);
      const float4 p1 = *reinterpret_cast<const float4*>(xr + c0 - 8);
      const float4 p2 = *reinterpret_cast<const float4*>(xr + c0 - 4);
      pv[0]=p0.x; pv[1]=p0.y; pv[2]=p0.z; pv[3]=p0.w;
      pv[4]=p1.x; pv[5]=p1.y; pv[6]=p1.z; pv[7]=p1.w;
      pv[8]=p2.x; pv[9]=p2.y; pv[10]=p2.z; pv[11]=p2.w;
    } else {
#pragma unroll
      for (int j = 0; j < 12; ++j) pv[j] = 0.f;
    }

    // stash z[8t+j] into packed layout: re at +rr, im at +2+rr (ds_write2 pairs)
#pragma unroll
    for (int j = 0; j < 8; ++j) {
      const int fo = FL8(8*t + j) * 4 + rr;
      buff[fo]     = vv[2*j];
      buff[fo + 2] = vv[2*j + 1];
    }

    // ---- per-thread stats (scalar) ----
    {
      float sumsq = 0.f, alt = 0.f;
#pragma unroll
      for (int j = 0; j < 16; ++j) {
        sumsq = fmaf(vv[j], vv[j], sumsq);
        alt += (j & 1) ? -vv[j] : vv[j];
      }
      float r;
      r = wave_red_add(sumsq); if (t == 63) st[0] = r;
      r = wave_red_add(alt);   if (t == 63) st[1] = r;
    }
#pragma unroll
    for (int k = 1; k <= 10; ++k) {
      float acc = 0.f;
#pragma unroll
      for (int j = 0; j < 16; ++j) acc = fmaf(vv[j], vv[j+k], acc);
      float r = wave_red_add(acc);
      if (t == 63) st[1 + k] = r;
    }

    // ---- prefix sums ----
    float s[16];
    s[0] = vv[0];
#pragma unroll
    for (int j = 1; j < 16; ++j) s[j] = s[j-1] + vv[j];
    const float cs16 = s[15];
    const float incl = wave_iscan_add(cs16);
    const float excl = incl - cs16;
#pragma unroll
    for (int j = 0; j < 16; ++j) s[j] += excl;
    if (t == 63) st[16] = incl;                       // SUMX
    if (t == 0) {
#pragma unroll
      for (int q = 0; q < 10; ++q) st[17 + q] = s[q];
      st[37] = vv[0];
    }
    if (t == 63) {
#pragma unroll
      for (int q = 0; q < 10; ++q) st[27 + q] = s[5 + q];
      st[38] = vv[15];
    }

    // ---- trend via sliding +-12 window ----
    float trv[16];
    float str = 0.f, str2 = 0.f;
    {
      float wsum = 0.f;
#pragma unroll
      for (int j = 0; j < 12; ++j) wsum += pv[j];
#pragma unroll
      for (int j = 0; j <= 12; ++j) wsum += vv[j];
#pragma unroll
      for (int jj = 0; jj < 16; ++jj) {
        if (jj > 0) {
          const float addv = vv[jj + 12];
          const float subv = (jj < 13) ? pv[jj - 1] : vv[jj - 13];
          wsum += addv - subv;
        }
        float swc = wsum;
        if (t == 0  && jj < 12) swc += (float)(12 - jj) * vv[0];
        if (t == 63 && jj >= 4) swc += (float)(jj - 3) * vv[15];
        const float tv = swc * 0.04f;
        trv[jj] = tv;
        str += tv;
        str2 = fmaf(tv, tv, str2);
      }
    }
    const float tincl = wave_iscan_add(str);
    if (t == 63) st[12] = tincl;
    { float r = wave_red_add(str2); if (t == 63) st[13] = r; }
    {
      const float texcl = tincl - str;
      float run = texcl, sc = 0.f, sc2 = 0.f;
#pragma unroll
      for (int jj = 0; jj < 16; ++jj) {
        run += trv[jj];
        const float cv = s[jj] - run;
        sc += cv;
        sc2 = fmaf(cv, cv, sc2);
      }
      float r;
      r = wave_red_add(sc);  if (t == 63) st[14] = r;
      r = wave_red_add(sc2); if (t == 63) st[15] = r;
    }
  }

  // ==================== packed half-length real FFT (2 rows per wave) ====================
  f2v zr[8], zi[8];
#pragma unroll
  for (int p = 0; p < 8; ++p) {
    const float4 q4 = *reinterpret_cast<const float4*>(&buff[FL8(t + 64*p) * 4]);
    zr[p] = f2v{q4.x, q4.y};
    zi[p] = f2v{q4.z, q4.w};
  }
  dft8p(zr, zi);
  {
    const float a1 = -0.012271846303085130f * (float)t;   // -2pi/512 * t
    const float c1 = __cosf(a1), s1 = __sinf(a1);
    const float c2=c1*c1-s1*s1, s2=2.f*c1*s1;
    const float c3=c2*c1-s2*s1, s3=s2*c1+c2*s1;
    const float c4=c2*c2-s2*s2, s4=2.f*c2*s2;
    const float c5=c4*c1-s4*s1, s5=s4*c1+c4*s1;
    const float c6=c3*c3-s3*s3, s6=2.f*c3*s3;
    const float c7=c6*c1-s6*s1, s7=s6*c1+c6*s1;
    const float cq[8] = {1.f,c1,c2,c3,c4,c5,c6,c7};
    const float sq[8] = {0.f,s1,s2,s3,s4,s5,s6,s7};
#pragma unroll
    for (int q = 1; q < 8; ++q) {
      const f2v r0 = zr[q]*cq[q] - zi[q]*sq[q];
      zi[q] = zr[q]*sq[q] + zi[q]*cq[q];
      zr[q] = r0;
    }
  }
  // transpose 1: unit q*64 + t
#pragma unroll
  for (int q = 0; q < 8; ++q) {
    const int fo = FL8(q*64 + t) * 4;
    *reinterpret_cast<f2v*>(&buff[fo])     = zr[q];
    *reinterpret_cast<f2v*>(&buff[fo + 2]) = zi[q];
  }
  const int qq = t >> 3;
  const int dd = t & 7;
  const int qb = qq << 6;
#pragma unroll
  for (int e = 0; e < 8; ++e) {
    const float4 q4 = *reinterpret_cast<const float4*>(&buff[FL8(qb + dd + 8*e) * 4]);
    zr[e] = f2v{q4.x, q4.y};
    zi[e] = f2v{q4.z, q4.w};
  }
  dft8p(zr, zi);
  {
    const float a1 = -0.098174770424681039f * (float)dd;  // -2pi/64 * d
    const float c1 = __cosf(a1), s1 = __sinf(a1);
    const float c2=c1*c1-s1*s1, s2=2.f*c1*s1;
    const float c3=c2*c1-s2*s1, s3=s2*c1+c2*s1;
    const float c4=c2*c2-s2*s2, s4=2.f*c2*s2;
    const float c5=c4*c1-s4*s1, s5=s4*c1+c4*s1;
    const float c6=c3*c3-s3*s3, s6=2.f*c3*s3;
    const float c7=c6*c1-s6*s1, s7=s6*c1+c6*s1;
    const float cq[8] = {1.f,c1,c2,c3,c4,c5,c6,c7};
    const float sq[8] = {0.f,s1,s2,s3,s4,s5,s6,s7};
#pragma unroll
    for (int q = 1; q < 8; ++q) {
      const f2v r0 = zr[q]*cq[q] - zi[q]*sq[q];
      zi[q] = zr[q]*sq[q] + zi[q]*cq[q];
      zr[q] = r0;
    }
  }
  // transpose 2: unit qb + sA*8 + dd
#pragma unroll
  for (int sA = 0; sA < 8; ++sA) {
    const int fo = FL8(qb + sA*8 + dd) * 4;
    *reinterpret_cast<f2v*>(&buff[fo])     = zr[sA];
    *reinterpret_cast<f2v*>(&buff[fo + 2]) = zi[sA];
  }
#pragma unroll
  for (int d = 0; d < 8; ++d) {
    const float4 q4 = *reinterpret_cast<const float4*>(&buff[FL8(qb + dd*8 + d) * 4]);
    zr[d] = f2v{q4.x, q4.y};
    zi[d] = f2v{q4.z, q4.w};
  }
  dft8p(zr, zi);
  // register r holds Z[k] (both rows), k = 64r + 8*dd + qq

  // ---- untangle to rfft psd: write Z, read conjugate partner ----
#pragma unroll
  for (int r = 0; r < 8; ++r) {
    const int fo = FL8(t*8 + r) * 4;
    *reinterpret_cast<f2v*>(&buff[fo])     = zr[r];
    *reinterpret_cast<f2v*>(&buff[fo + 2]) = zi[r];
  }
  const int pl = (t == 0) ? 0 : ((t < 8) ? (8 - t) : (71 - t));
  const bool lane0 = (t == 0);
  const float kb = (float)((dd << 3) + qq);
  const float ab = -0.0061359231515425649f * kb;          // -pi/512 * (8s+q)
  const float wbr = __cosf(ab), wbi = __sinf(ab);
  constexpr float RCr[8] = {1.f, 0.98078528040323044f, 0.92387953251128674f, 0.83146961230254524f,
                            0.70710678118654752f, 0.55557023301960222f, 0.38268343236508977f, 0.19509032201612827f};
  constexpr float RCi[8] = {0.f, -0.19509032201612827f, -0.38268343236508977f, -0.55557023301960222f,
                            -0.70710678118654752f, -0.83146961230254524f, -0.92387953251128674f, -0.98078528040323044f};
  float psA = 0.f, psB = 0.f, pmA = 0.f, pmB = 0.f, plA = 0.f, plB = 0.f;
#pragma unroll
  for (int r = 0; r < 8; ++r) {
    const int rho = lane0 ? ((8 - r) & 7) : (7 - r);
    const float4 q4 = *reinterpret_cast<const float4*>(&buff[FL8(pl*8 + rho) * 4]);
    const f2v zpr = f2v{q4.x, q4.y};
    const f2v zpi = f2v{q4.z, q4.w};
    const f2v Er = 0.5f*(zr[r] + zpr);
    const f2v Ei = 0.5f*(zi[r] - zpi);
    const f2v Or = 0.5f*(zi[r] + zpi);
    const f2v Oi = -0.5f*(zr[r] - zpr);
    const float wr = wbr*RCr[r] - wbi*RCi[r];
    const float wi = wbr*RCi[r] + wbi*RCr[r];
    const f2v Xr = Er + wr*Or - wi*Oi;
    const f2v Xi = Ei + wr*Oi + wi*Or;
    const f2v pp = Xr*Xr + Xi*Xi;
    const float pa = fmaxf(pp.x, EPSF);
    const float pb = fmaxf(pp.y, EPSF);
    psA += pa; psB += pb;
    pmA = fmaxf(pmA, pa); pmB = fmaxf(pmB, pb);
    plA += pa * __logf(pa);
    plB += pb * __logf(pb);
  }
  float PSUM2[2], PMAX2[2], PLOG2[2];
  PSUM2[0] = rl(wave_red_add(psA), 63);
  PSUM2[1] = rl(wave_red_add(psB), 63);
  PMAX2[0] = rl(wave_red_max_pos(pmA), 63);
  PMAX2[1] = rl(wave_red_max_pos(pmB), 63);
  PLOG2[0] = rl(wave_red_add(plA), 63);
  PLOG2[1] = rl(wave_red_add(plB), 63);

  // ======== per-row tail: features, LN, MLP, stores ========
#pragma unroll 1
  for (int rr = 0; rr < 2; ++rr) {
    const float* st = stats2[wv][rr];
    const int row = rowbase + rr;
    const float PSUM = PSUM2[rr], PMAX = PMAX2[rr], PLOG = PLOG2[rr];

    const float SUMSQ = st[0];
    const float ALT   = st[1];
    const float STR   = st[12];
    const float STR2  = st[13];
    const float SC    = st[14];
    const float SC2   = st[15];
    const float SUMX  = st[16];
    const float x0    = st[37];
    const float xl    = st[38];

    const float p512b = fmaxf(ALT * ALT, EPSF);
    const float Sr    = PSUM + p512b;
    const float invS  = 1.f / Sr;
    const float PLr   = PLOG + p512b * __logf(p512b);
    const float ent   = __logf(Sr) - PLr * invS;
    const float PMX   = fmaxf(PMAX, p512b);

    const float m = SUMX * (1.f / 1024.f);
    const float den = SUMSQ - 1024.f * m * m + EPSF;
    const float invden = 1.f / den;
    float acf1 = 0.f, acf2 = 0.f, lbq = 0.f, R1v = 0.f;
#pragma unroll
    for (int k = 1; k <= 10; ++k) {
      const float Rkv = st[1 + k];
      const float Slo = st[16 + k];
      const float Shi = st[37 - k];
      const float num = Rkv - m * (Shi + (SUMX - Slo)) + (float)(1024 - k) * m * m;
      const float a = fminf(fmaxf(num * invden, -1.f), 1.f);
      if (k == 1) { acf1 = a; R1v = Rkv; }
      else if (k == 2) acf2 = a;
      lbq += a * a;
    }
    const float spent = fminf(fmaxf(ent / (__logf(513.f + EPSF) + EPSF), 0.f), 1.f);
    const float peak  = fminf(fmaxf(PMX / (Sr + EPSF), 0.f), 1.f);
    const float phi = fminf(fmaxf(R1v / ((SUMSQ - xl * xl) + EPSF), -1.f), 1.f);
    const float invn = 1.f / 1023.f;
    const float sum_d2 = 2.f * SUMSQ - x0 * x0 - xl * xl - 2.f * R1v;
    const float md = (xl - x0) * invn;
    const float diff_var = sum_d2 * invn - md * md;
    const float tstr = STR2 * (1.f / 1024.f) - (STR * (1.f / 1024.f)) * (STR * (1.f / 1024.f));
    const float varx = SUMSQ * (1.f / 1024.f) - m * m;
    const float mc = SC * (1.f / 1024.f);
    const float kpss = (SC2 * (1.f / 1024.f) - mc * mc) / (varx + 1e-8f);

    float f[9] = {acf1, acf2, spent, phi, diff_var, tstr, kpss, lbq, peak};
    float fm = 0.f;
#pragma unroll
    for (int d = 0; d < 9; ++d) fm += f[d];
    fm *= (1.f / 9.f);
    float fv = 0.f;
#pragma unroll
    for (int d = 0; d < 9; ++d) { const float tt = f[d] - fm; fv = fmaf(tt, tt, fv); }
    fv *= (1.f / 9.f);
    const float inl = 1.f / sqrtf(fv + 1e-5f);
    float fn[9];
#pragma unroll
    for (int d = 0; d < 9; ++d) fn[d] = (f[d] - fm) * inl * ln_w[d] + ln_b[d];

    float h = b1[t];
#pragma unroll
    for (int d = 0; d < 9; ++d) h = fmaf(fn[d], w1[d * 64 + t], h);
    h = fmaxf(h, 0.f);
    float l0 = h * w2[t * 3 + 0];
    float l1 = h * w2[t * 3 + 1];
    float l2 = h * w2[t * 3 + 2];
    l0 = wave_red_add(l0);
    l1 = wave_red_add(l1);
    l2 = wave_red_add(l2);
    const float L0 = rl(l0, 63) + b2[0];
    const float L1 = rl(l1, 63) + b2[1];
    const float L2 = rl(l2, 63) + b2[2];
    if (t == 0) {
      const float mx = fmaxf(L0, fmaxf(L1, L2));
      const float e0 = __expf(L0 - mx), e1 = __expf(L1 - mx), e2 = __expf(L2 - mx);
      const float is = 1.f / (e0 + e1 + e2);
      float* o = out + (size_t)row * 3;
      o[0] = e0 * is; o[1] = e1 * is; o[2] = e2 * is;
      float* fo = out + (size_t)B * 3 + (size_t)row * 9;
      fo[0] = fn[0]; fo[1] = fn[1]; fo[2] = fn[2]; fo[3] = fn[3]; fo[4] = fn[4];
      fo[5] = fn[5]; fo[6] = fn[6]; fo[7] = fn[7]; fo[8] = fn[8];
    }
  }
}

extern "C" void kernel_launch(void* const* d_in, const int* in_sizes, int n_in,
                              void* d_out, int out_size, void* d_ws, size_t ws_size,
                              hipStream_t stream) {
  (void)n_in; (void)out_size; (void)d_ws; (void)ws_size;
  const float* x    = (const float*)d_in[0];
  const float* ln_w = (const float*)d_in[1];
  const float* ln_b = (const float*)d_in[2];
  const float* w1   = (const float*)d_in[3];
  const float* b1   = (const float*)d_in[4];
  const float* w2   = (const float*)d_in[5];
  const float* b2   = (const float*)d_in[6];
  float* out = (float*)d_out;
  const int B = in_sizes[0] / 1024;
  sr_kernel<<<(B + 3) / 4, 128, 0, stream>>>(x, ln_w, ln_b, w1, b1, w2, b2, out, B);
}